// Round 2
// baseline (495.331 us; speedup 1.0000x reference)
//
#include <hip/hip_runtime.h>

#define SEQ   512
#define BATCH 64
#define HID   1024
#define NX    8

// ---------------------------------------------------------------------------
// WVT[h][n] = WV[n][h]  (one-time 32x32 tiled transpose)
// ---------------------------------------------------------------------------
__global__ __launch_bounds__(256) void transpose_k(
    const float* __restrict__ in, float* __restrict__ outT)
{
    __shared__ float tile[32][33];
    const int bx = blockIdx.x * 32, by = blockIdx.y * 32;
    const int tx = threadIdx.x & 31, ty = threadIdx.x >> 5;   // ty 0..7
    #pragma unroll
    for (int r = ty; r < 32; r += 8)
        tile[r][tx] = in[(size_t)(by + r) * HID + bx + tx];
    __syncthreads();
    #pragma unroll
    for (int r = ty; r < 32; r += 8)
        outT[(size_t)(bx + r) * HID + by + tx] = tile[tx][r];
}

__global__ __launch_bounds__(256) void copy_q_kernel(
    const float* __restrict__ q, float* __restrict__ out)
{
    const int idx = blockIdx.x * 256 + threadIdx.x;   // 0 .. BATCH*HID-1
    const int b = idx >> 10;
    const int h = idx & (HID - 1);
    out[(size_t)(b * NX) * HID + h] = q[(size_t)b * HID + h];
}

// ---------------------------------------------------------------------------
// yp[b, jg, h] = sum_{j in jg} x[b,j] * WK[j,h]      grid (4 hc, 8 jg, 64 b)
// x = out[(b*NX + t-1)*HID + j]
// ---------------------------------------------------------------------------
__global__ __launch_bounds__(256) void gemv_y_kernel(
    const float* __restrict__ WK, const float* __restrict__ out, int t,
    float* __restrict__ yp)
{
    const int h  = blockIdx.x * 256 + threadIdx.x;
    const int jg = blockIdx.y;
    const int b  = blockIdx.z;
    const float* __restrict__ x = out + (size_t)(b * NX + t - 1) * HID + jg * 128;
    const float* __restrict__ wk = WK + (size_t)(jg * 128) * HID + h;
    float acc = 0.f;
    #pragma unroll 8
    for (int j = 0; j < 128; j++)
        acc += x[j] * wk[(size_t)j * HID];
    yp[((size_t)b * 8 + jg) * HID + h] = acc;
}

// part [64][8][1024] -> full [64][1024]
__global__ __launch_bounds__(256) void reduce8_kernel(
    const float* __restrict__ part, float* __restrict__ full)
{
    const int idx = blockIdx.x * 256 + threadIdx.x;
    const int b = idx >> 10, h = idx & (HID - 1);
    float s = 0.f;
    #pragma unroll
    for (int g = 0; g < 8; g++) s += part[((size_t)b * 8 + g) * HID + h];
    full[idx] = s;
}

// part [64][8][1024] + bias -> out[(b*NX+t)*HID + n]
__global__ __launch_bounds__(256) void reduce8_bias_kernel(
    const float* __restrict__ part, const float* __restrict__ bias,
    float* __restrict__ out, int t)
{
    const int idx = blockIdx.x * 256 + threadIdx.x;
    const int b = idx >> 10, n = idx & (HID - 1);
    float s = bias[n];
    #pragma unroll
    for (int g = 0; g < 8; g++) s += part[((size_t)b * 8 + g) * HID + n];
    out[((size_t)b * NX + t) * HID + n] = s;
}

// ---------------------------------------------------------------------------
// scores[b,s] = sum_h y[b,h] * hidden[s,b,h]     (one wave per hidden row)
// ---------------------------------------------------------------------------
__global__ __launch_bounds__(256) void scores_kernel(
    const float* __restrict__ hidden, const float* __restrict__ y,
    float* __restrict__ scores)
{
    const int gid  = blockIdx.x * 4 + (threadIdx.x >> 6);  // row = s*64 + b
    const int lane = threadIdx.x & 63;
    const int b = gid & (BATCH - 1);
    const int s = gid >> 6;

    const float* hp = hidden + (size_t)gid * HID + lane * 16;
    const float* ypr = y + (size_t)b * HID + lane * 16;

    float sum = 0.f;
    #pragma unroll
    for (int i = 0; i < 4; i++) {
        float4 hv = *(const float4*)(hp + i * 4);
        float4 yv = *(const float4*)(ypr + i * 4);
        sum += hv.x * yv.x + hv.y * yv.y + hv.z * yv.z + hv.w * yv.w;
    }
    #pragma unroll
    for (int off = 32; off; off >>= 1) sum += __shfl_xor(sum, off);
    if (lane == 0) scores[b * SEQ + s] = sum;
}

// ---------------------------------------------------------------------------
// attn[b,s] = softmax_s(scores[b,s])      grid 64 blocks x 256
// ---------------------------------------------------------------------------
__global__ __launch_bounds__(256) void softmax_kernel(
    const float* __restrict__ scores, float* __restrict__ attn)
{
    const int b = blockIdx.x;
    const int tid = threadIdx.x;
    const int w = tid >> 6, lane = tid & 63;
    __shared__ float red[8];

    float v0 = scores[b * SEQ + tid];
    float v1 = scores[b * SEQ + tid + 256];
    float mx = fmaxf(v0, v1);
    #pragma unroll
    for (int off = 32; off; off >>= 1) mx = fmaxf(mx, __shfl_xor(mx, off));
    if (lane == 0) red[w] = mx;
    __syncthreads();
    mx = fmaxf(fmaxf(red[0], red[1]), fmaxf(red[2], red[3]));

    float e0 = expf(v0 - mx), e1 = expf(v1 - mx);
    float se = e0 + e1;
    #pragma unroll
    for (int off = 32; off; off >>= 1) se += __shfl_xor(se, off);
    if (lane == 0) red[4 + w] = se;
    __syncthreads();
    const float inv = 1.0f / (red[4] + red[5] + red[6] + red[7]);
    attn[b * SEQ + tid] = e0 * inv;
    attn[b * SEQ + tid + 256] = e1 * inv;
}

// ---------------------------------------------------------------------------
// zp[b, sg, h] = sum_{s in sg} attn[b,s] * hidden[s,b,h]   grid (4 hc, 8 sg, 64 b)
// ---------------------------------------------------------------------------
__global__ __launch_bounds__(256) void zsum_kernel(
    const float* __restrict__ hidden, const float* __restrict__ attn,
    float* __restrict__ zp)
{
    const int h  = blockIdx.x * 256 + threadIdx.x;
    const int sg = blockIdx.y;
    const int b  = blockIdx.z;
    const float* __restrict__ ap = attn + b * SEQ + sg * 64;
    const float* __restrict__ hp = hidden + ((size_t)(sg * 64) * BATCH + b) * HID + h;
    float acc = 0.f;
    #pragma unroll 8
    for (int si = 0; si < 64; si++)
        acc += ap[si] * hp[(size_t)si * BATCH * HID];
    zp[((size_t)b * 8 + sg) * HID + h] = acc;
}

// ---------------------------------------------------------------------------
// op[b, hg, n] = sum_{h in hg} z[b,h] * WVT[h,n]    grid (4 nc, 8 hg, 64 b)
// ---------------------------------------------------------------------------
__global__ __launch_bounds__(256) void gemv_out_kernel(
    const float* __restrict__ WVT, const float* __restrict__ z,
    float* __restrict__ op)
{
    const int n  = blockIdx.x * 256 + threadIdx.x;
    const int hg = blockIdx.y;
    const int b  = blockIdx.z;
    const float* __restrict__ zb = z + (size_t)b * HID + hg * 128;
    const float* __restrict__ wv = WVT + (size_t)(hg * 128) * HID + n;
    float acc = 0.f;
    #pragma unroll 8
    for (int h = 0; h < 128; h++)
        acc += zb[h] * wv[(size_t)h * HID];
    op[((size_t)b * 8 + hg) * HID + n] = acc;
}

// ---------------------------------------------------------------------------
extern "C" void kernel_launch(void* const* d_in, const int* in_sizes, int n_in,
                              void* d_out, int out_size, void* d_ws, size_t ws_size,
                              hipStream_t stream)
{
    const float* hidden = (const float*)d_in[1];
    const float* q      = (const float*)d_in[2];
    const float* WK     = (const float*)d_in[3];
    const float* WV     = (const float*)d_in[5];
    const float* bV     = (const float*)d_in[6];
    float* out = (float*)d_out;

    char* ws = (char*)d_ws;
    float* WVT    = (float*)(ws);                      // 4 MiB
    float* yp     = (float*)(ws + (4 << 20));          // 2 MiB  (also reused as op)
    float* y      = (float*)(ws + (6 << 20));          // 256 KiB
    float* scores = (float*)(ws + (6 << 20) + (256 << 10));   // 128 KiB
    float* attn   = (float*)(ws + (6 << 20) + (384 << 10));   // 128 KiB
    float* zp     = (float*)(ws + (6 << 20) + (512 << 10));   // 2 MiB
    float* z      = (float*)(ws + (8 << 20) + (512 << 10));   // 256 KiB

    transpose_k<<<dim3(32, 32), 256, 0, stream>>>(WV, WVT);
    copy_q_kernel<<<(BATCH * HID) / 256, 256, 0, stream>>>(q, out);

    for (int t = 1; t < NX; t++) {
        gemv_y_kernel<<<dim3(4, 8, BATCH), 256, 0, stream>>>(WK, out, t, yp);
        reduce8_kernel<<<(BATCH * HID) / 256, 256, 0, stream>>>(yp, y);
        scores_kernel<<<(BATCH * SEQ) / 4, 256, 0, stream>>>(hidden, y, scores);
        softmax_kernel<<<BATCH, 256, 0, stream>>>(scores, attn);
        zsum_kernel<<<dim3(4, 8, BATCH), 256, 0, stream>>>(hidden, attn, zp);
        reduce8_kernel<<<(BATCH * HID) / 256, 256, 0, stream>>>(zp, z);
        gemv_out_kernel<<<dim3(4, 8, BATCH), 256, 0, stream>>>(WVT, z, yp);
        reduce8_bias_kernel<<<(BATCH * HID) / 256, 256, 0, stream>>>(yp, bV, out, t);
    }
}